// Round 4
// baseline (386.719 us; speedup 1.0000x reference)
//
#include <hip/hip_runtime.h>
#include <math.h>

typedef unsigned int uint;
typedef unsigned short ushort;
typedef unsigned char uchar;
typedef __attribute__((ext_vector_type(2))) float v2f;

#define S1 4.0f
#define S2 16.0f

template <bool HI>
__device__ inline v2f fp8x2f(uint u) {
    return __builtin_amdgcn_cvt_pk_f32_fp8((int)u, HI);
}

// ---- GEMM1: h1f8[N,64](fp8,x4) = x[N,128] @ W1[128,64], fused al1s/al1d ----
__global__ __launch_bounds__(256) void k_gemm1(const float* __restrict__ x,
                                               const float* __restrict__ W1,
                                               const float* __restrict__ as1,
                                               const float* __restrict__ ad1,
                                               uchar* __restrict__ h1f8,
                                               float* __restrict__ al1s,
                                               float* __restrict__ al1d, int N) {
    __shared__ float sB[128 * 64];
    __shared__ float sA[64 * 68];
    const int t = threadIdx.x;
    const int n0 = blockIdx.x * 64;
    {
        const float4* w4 = (const float4*)W1;
        float4* s4 = (float4*)sB;
#pragma unroll
        for (int i = 0; i < 8; ++i) s4[t + i * 256] = w4[t + i * 256];
    }
    const int r0 = (t >> 3) * 2;
    const int c0 = (t & 7) * 8;   // head = t&7, channels c0..c0+7
    float acc0[8] = {0, 0, 0, 0, 0, 0, 0, 0};
    float acc1[8] = {0, 0, 0, 0, 0, 0, 0, 0};
    for (int kb = 0; kb < 2; ++kb) {
        __syncthreads();
#pragma unroll
        for (int i = 0; i < 4; ++i) {
            int idx = t + i * 256;
            int r = idx >> 4, kc = idx & 15;
            int n = n0 + r;
            float4 v = make_float4(0.f, 0.f, 0.f, 0.f);
            if (n < N) v = ((const float4*)x)[(size_t)n * 32 + kb * 16 + kc];
            *(float4*)&sA[r * 68 + kc * 4] = v;
        }
        __syncthreads();
        const float* bptr = &sB[kb * 64 * 64];
#pragma unroll 8
        for (int kk = 0; kk < 64; ++kk) {
            float a0 = sA[r0 * 68 + kk];
            float a1 = sA[(r0 + 1) * 68 + kk];
            const float* bp = &bptr[kk * 64 + c0];
            float4 b0 = *(const float4*)bp;
            float4 b1v = *(const float4*)(bp + 4);
            acc0[0] += a0 * b0.x; acc0[1] += a0 * b0.y; acc0[2] += a0 * b0.z; acc0[3] += a0 * b0.w;
            acc0[4] += a0 * b1v.x; acc0[5] += a0 * b1v.y; acc0[6] += a0 * b1v.z; acc0[7] += a0 * b1v.w;
            acc1[0] += a1 * b0.x; acc1[1] += a1 * b0.y; acc1[2] += a1 * b0.z; acc1[3] += a1 * b0.w;
            acc1[4] += a1 * b1v.x; acc1[5] += a1 * b1v.y; acc1[6] += a1 * b1v.z; acc1[7] += a1 * b1v.w;
        }
    }
    float ps0 = 0.f, pd0 = 0.f, ps1 = 0.f, pd1 = 0.f;
#pragma unroll
    for (int i = 0; i < 8; ++i) {
        float ws = as1[c0 + i], wd = ad1[c0 + i];
        ps0 += acc0[i] * ws; pd0 += acc0[i] * wd;
        ps1 += acc1[i] * ws; pd1 += acc1[i] * wd;
    }
    int n = n0 + r0;
    int head = t & 7;
    if (n < N) {
        int q0 = 0, q1 = 0;
        q0 = __builtin_amdgcn_cvt_pk_fp8_f32(acc0[0] * S1, acc0[1] * S1, q0, false);
        q0 = __builtin_amdgcn_cvt_pk_fp8_f32(acc0[2] * S1, acc0[3] * S1, q0, true);
        q1 = __builtin_amdgcn_cvt_pk_fp8_f32(acc0[4] * S1, acc0[5] * S1, q1, false);
        q1 = __builtin_amdgcn_cvt_pk_fp8_f32(acc0[6] * S1, acc0[7] * S1, q1, true);
        uint2 p; p.x = (uint)q0; p.y = (uint)q1;
        *(uint2*)&h1f8[(size_t)n * 64 + c0] = p;
        al1s[(size_t)n * 8 + head] = ps0;
        al1d[(size_t)n * 8 + head] = pd0;
    }
    if (n + 1 < N) {
        int q0 = 0, q1 = 0;
        q0 = __builtin_amdgcn_cvt_pk_fp8_f32(acc1[0] * S1, acc1[1] * S1, q0, false);
        q0 = __builtin_amdgcn_cvt_pk_fp8_f32(acc1[2] * S1, acc1[3] * S1, q0, true);
        q1 = __builtin_amdgcn_cvt_pk_fp8_f32(acc1[4] * S1, acc1[5] * S1, q1, false);
        q1 = __builtin_amdgcn_cvt_pk_fp8_f32(acc1[6] * S1, acc1[7] * S1, q1, true);
        uint2 p; p.x = (uint)q0; p.y = (uint)q1;
        *(uint2*)&h1f8[(size_t)(n + 1) * 64 + c0] = p;
        al1s[(size_t)(n + 1) * 8 + head] = ps1;
        al1d[(size_t)(n + 1) * 8 + head] = pd1;
    }
}

// ---- GEMM2: h2f8[N,128](fp8,x16) = relu(x1pre+b1) @ W2[64,128], fused al2 ----
__global__ __launch_bounds__(256) void k_gemm2(const float* __restrict__ x1pre,
                                               const float* __restrict__ W2,
                                               const float* __restrict__ b1,
                                               const float* __restrict__ as2,
                                               const float* __restrict__ ad2,
                                               uchar* __restrict__ h2f8,
                                               float* __restrict__ al2s,
                                               float* __restrict__ al2d, int N) {
    __shared__ float sB[64 * 128];
    __shared__ float sA[64 * 68];
    const int t = threadIdx.x;
    const int n0 = blockIdx.x * 64;
    {
        const float4* w4 = (const float4*)W2;
        float4* s4 = (float4*)sB;
#pragma unroll
        for (int i = 0; i < 8; ++i) s4[t + i * 256] = w4[t + i * 256];
    }
#pragma unroll
    for (int i = 0; i < 4; ++i) {
        int idx = t + i * 256;
        int r = idx >> 4, kc = idx & 15;
        int n = n0 + r;
        float4 v = make_float4(0.f, 0.f, 0.f, 0.f);
        if (n < N) {
            v = ((const float4*)x1pre)[(size_t)n * 16 + kc];
            float4 bb = ((const float4*)b1)[kc];
            v.x = fmaxf(v.x + bb.x, 0.f);
            v.y = fmaxf(v.y + bb.y, 0.f);
            v.z = fmaxf(v.z + bb.z, 0.f);
            v.w = fmaxf(v.w + bb.w, 0.f);
        }
        *(float4*)&sA[r * 68 + kc * 4] = v;
    }
    __syncthreads();
    const int r0 = (t >> 3) * 2;
    const int cb = (t & 7) * 4;
    float acc0[16], acc1[16];
#pragma unroll
    for (int i = 0; i < 16; ++i) { acc0[i] = 0.f; acc1[i] = 0.f; }
#pragma unroll 4
    for (int k = 0; k < 64; ++k) {
        float a0 = sA[r0 * 68 + k];
        float a1 = sA[(r0 + 1) * 68 + k];
#pragma unroll
        for (int j = 0; j < 4; ++j) {
            float4 b = *(const float4*)&sB[k * 128 + cb + 32 * j];
            acc0[j * 4 + 0] += a0 * b.x; acc0[j * 4 + 1] += a0 * b.y;
            acc0[j * 4 + 2] += a0 * b.z; acc0[j * 4 + 3] += a0 * b.w;
            acc1[j * 4 + 0] += a1 * b.x; acc1[j * 4 + 1] += a1 * b.y;
            acc1[j * 4 + 2] += a1 * b.z; acc1[j * 4 + 3] += a1 * b.w;
        }
    }
    float ps0 = 0.f, pd0 = 0.f, ps1 = 0.f, pd1 = 0.f;
#pragma unroll
    for (int j = 0; j < 4; ++j)
#pragma unroll
        for (int i = 0; i < 4; ++i) {
            int cc = cb + 32 * j + i;
            float ws = as2[cc], wd = ad2[cc];
            ps0 += acc0[j * 4 + i] * ws; pd0 += acc0[j * 4 + i] * wd;
            ps1 += acc1[j * 4 + i] * ws; pd1 += acc1[j * 4 + i] * wd;
        }
#pragma unroll
    for (int off = 1; off < 8; off <<= 1) {
        ps0 += __shfl_xor(ps0, off); pd0 += __shfl_xor(pd0, off);
        ps1 += __shfl_xor(ps1, off); pd1 += __shfl_xor(pd1, off);
    }
    int n = n0 + r0;
    if (n < N) {
#pragma unroll
        for (int j = 0; j < 4; ++j) {
            int q = 0;
            q = __builtin_amdgcn_cvt_pk_fp8_f32(acc0[j * 4 + 0] * S2, acc0[j * 4 + 1] * S2, q, false);
            q = __builtin_amdgcn_cvt_pk_fp8_f32(acc0[j * 4 + 2] * S2, acc0[j * 4 + 3] * S2, q, true);
            *(uint*)&h2f8[(size_t)n * 128 + cb + 32 * j] = (uint)q;
        }
        if ((t & 7) == 0) { al2s[n] = ps0; al2d[n] = pd0; }
    }
    if (n + 1 < N) {
#pragma unroll
        for (int j = 0; j < 4; ++j) {
            int q = 0;
            q = __builtin_amdgcn_cvt_pk_fp8_f32(acc1[j * 4 + 0] * S2, acc1[j * 4 + 1] * S2, q, false);
            q = __builtin_amdgcn_cvt_pk_fp8_f32(acc1[j * 4 + 2] * S2, acc1[j * 4 + 3] * S2, q, true);
            *(uint*)&h2f8[(size_t)(n + 1) * 128 + cb + 32 * j] = (uint)q;
        }
        if ((t & 7) == 0) { al2s[n + 1] = ps1; al2d[n + 1] = pd1; }
    }
}

// ========== atomic-free CSR build: two-level counting sort ==========
// buckets: dst >> 7 (128 nodes each). All fine-grained atomics are LDS-local.

// pass A: per-block LDS histogram over buckets
__global__ __launch_bounds__(256) void k_hist(const int* __restrict__ dst,
                                              int* __restrict__ counts,
                                              int E, int CH, int NB) {
    __shared__ int hist[784];
    int t = threadIdx.x, b = blockIdx.x;
    for (int k = t; k < NB; k += 256) hist[k] = 0;
    __syncthreads();
    int e0 = b * CH;
    int e1 = e0 + CH; if (e1 > E) e1 = E;
    for (int e = e0 + t; e < e1; e += 256)
        atomicAdd(&hist[dst[e] >> 7], 1);
    __syncthreads();
    for (int k = t; k < NB; k += 256) counts[(size_t)b * NB + k] = hist[k];
}

// pass B: per-bucket exclusive scan over blocks (one block per bucket)
__global__ __launch_bounds__(256) void k_bscan(int* __restrict__ counts,
                                               int* __restrict__ btot,
                                               int C, int NB) {
    __shared__ int sh[256];
    int t = threadIdx.x, k = blockIdx.x;
    int v[4];
#pragma unroll
    for (int i = 0; i < 4; ++i) {
        int b = t * 4 + i;
        v[i] = (b < C) ? counts[(size_t)b * NB + k] : 0;
    }
    int s = v[0] + v[1] + v[2] + v[3];
    sh[t] = s;
    __syncthreads();
    int accv = s;
    for (int off = 1; off < 256; off <<= 1) {
        int u = (t >= off) ? sh[t - off] : 0;
        __syncthreads();
        accv += u;
        sh[t] = accv;
        __syncthreads();
    }
    int excl = accv - s;
#pragma unroll
    for (int i = 0; i < 4; ++i) {
        int b = t * 4 + i;
        if (b < C) counts[(size_t)b * NB + k] = excl;
        excl += v[i];
    }
    if (t == 255) btot[k] = accv;
}

// pass D: scatter edges into bucket-sorted ebuf (LDS returning atomics only)
// bbase scan folded in: every block recomputes the bucket-base prefix from btot;
// block 0 publishes it for k_csr. packed: src bits 0..24, dst&127 bits 25..31
__global__ __launch_bounds__(256) void k_bucket(const int* __restrict__ src,
                                                const int* __restrict__ dst,
                                                const int* __restrict__ counts,
                                                const int* __restrict__ btot,
                                                int* __restrict__ bbase,
                                                int* __restrict__ ebuf,
                                                int E, int CH, int NB) {
    __shared__ int pos[784];
    __shared__ int sh[256];
    __shared__ int bb[784];
    int t = threadIdx.x, b = blockIdx.x;
    // local exclusive scan of btot[0..NB) into bb
    int v[4];
#pragma unroll
    for (int i = 0; i < 4; ++i) {
        int k = t * 4 + i;
        v[i] = (k < NB) ? btot[k] : 0;
    }
    int s = v[0] + v[1] + v[2] + v[3];
    sh[t] = s;
    __syncthreads();
    int accv = s;
    for (int off = 1; off < 256; off <<= 1) {
        int u = (t >= off) ? sh[t - off] : 0;
        __syncthreads();
        accv += u;
        sh[t] = accv;
        __syncthreads();
    }
    int excl = accv - s;
#pragma unroll
    for (int i = 0; i < 4; ++i) {
        int k = t * 4 + i;
        if (k < NB) bb[k] = excl;
        excl += v[i];
    }
    __syncthreads();
    for (int k = t; k < NB; k += 256)
        pos[k] = bb[k] + counts[(size_t)b * NB + k];
    if (b == 0) {
        for (int k = t; k < NB; k += 256) bbase[k] = bb[k];
        if (t == 0) bbase[NB] = E;
    }
    __syncthreads();
    int e0 = b * CH;
    int e1 = e0 + CH; if (e1 > E) e1 = E;
    for (int e = e0 + t; e < e1; e += 256) {
        int d = dst[e], s2 = src[e];
        int p = atomicAdd(&pos[d >> 7], 1);
        ebuf[p] = (int)((uint)s2 | ((uint)(d & 127) << 25));
    }
}

// pass E: per-bucket fine CSR (count -> scan -> row_ptr + self-loop + local scatter)
__global__ __launch_bounds__(256) void k_csr(const int* __restrict__ bbase,
                                             const int* __restrict__ ebuf,
                                             int* __restrict__ row_ptr,
                                             int* __restrict__ col,
                                             int N, int E) {
    __shared__ int cnt[128];
    __shared__ int fill[128];
    __shared__ int rowb[128];
    __shared__ int sh[256];
    int t = threadIdx.x, k = blockIdx.x;
    int lo = bbase[k], hi = bbase[k + 1];
    int nlo = k << 7;
    int nn = N - nlo; if (nn > 128) nn = 128;
    if (t < 128) { cnt[t] = 0; fill[t] = 0; }
    __syncthreads();
    for (int i = lo + t; i < hi; i += 256)
        atomicAdd(&cnt[((uint)ebuf[i]) >> 25], 1);
    __syncthreads();
    int v = (t < nn) ? (cnt[t] + 1) : 0;  // +1 self-loop slot
    sh[t] = v;
    __syncthreads();
    int accv = v;
    for (int off = 1; off < 256; off <<= 1) {
        int u = (t >= off) ? sh[t - off] : 0;
        __syncthreads();
        accv += u;
        sh[t] = accv;
        __syncthreads();
    }
    int fbase = lo + nlo;  // global final offset = edge prefix + self-loop prefix
    if (t < nn) {
        int rb = fbase + accv - v;
        rowb[t] = rb;
        row_ptr[nlo + t] = rb;
        col[rb + cnt[t]] = nlo + t;  // self-loop at end of row
    }
    if (k == 0 && t == 0) row_ptr[N] = E + N;
    __syncthreads();
    for (int i = lo + t; i < hi; i += 256) {
        uint e = (uint)ebuf[i];
        int j = (int)(e >> 25);
        int r = atomicAdd(&fill[j], 1);
        col[rowb[j] + r] = (int)(e & 0x1FFFFFFu);
    }
}

// ---- edge1: wave/node, shfl-free inner loop ----
__global__ __launch_bounds__(256) void k_edge1(const uchar* __restrict__ h1f8,
                                               const float* __restrict__ al1s,
                                               const float* __restrict__ al1d,
                                               const int* __restrict__ row_ptr,
                                               const int* __restrict__ col,
                                               float* __restrict__ x1pre, int N) {
    int node = blockIdx.x * 4 + (threadIdx.x >> 6);
    if (node >= N) return;
    const int lane = threadIdx.x & 63;
    const int g = lane >> 4;       // edge subgroup 0..3
    const int k4 = lane & 15;      // channel quad (ch 4k4..4k4+3)
    const int hh = k4 >> 1;        // head of those channels
    const uint co = (uint)(k4 * 4);
    const float a_dh = al1d[(((uint)node) << 3) | (uint)hh];
    const int s0 = row_ptr[node], s1 = row_ptr[node + 1];
    float den_part = 0.f;
    v2f accL = {0.f, 0.f};
    v2f accH = {0.f, 0.f};
    for (int base = s0; base < s1; base += 64) {
        int cnt = s1 - base; if (cnt > 64) cnt = 64;
        int cntR = (cnt + 3) & ~3;
        int i = 0;
        for (; i + 16 <= cntR; i += 16) {
            int eA = base + i + g, eB = eA + 4, eC = eA + 8, eD = eA + 12;
            int xD = eD < s1 ? eD : s1 - 1;       // only D can run past
            int cA = col[eA], cB = col[eB], cC = col[eC], cD = col[xD];
            uint hA = *(const uint*)(h1f8 + ((((uint)cA) << 6) | co));
            uint hB = *(const uint*)(h1f8 + ((((uint)cB) << 6) | co));
            uint hC = *(const uint*)(h1f8 + ((((uint)cC) << 6) | co));
            uint hD = *(const uint*)(h1f8 + ((((uint)cD) << 6) | co));
            float lA = al1s[((((uint)cA) << 3) | (uint)hh)] + a_dh;
            float lB = al1s[((((uint)cB) << 3) | (uint)hh)] + a_dh;
            float lC = al1s[((((uint)cC) << 3) | (uint)hh)] + a_dh;
            float lD = al1s[((((uint)cD) << 3) | (uint)hh)] + a_dh;
            lA = lA > 0.f ? lA : 0.2f * lA;
            lB = lB > 0.f ? lB : 0.2f * lB;
            lC = lC > 0.f ? lC : 0.2f * lC;
            lD = lD > 0.f ? lD : 0.2f * lD;
            float wA = __expf(lA);
            float wB = __expf(lB);
            float wC = __expf(lC);
            float wD = (eD < s1) ? __expf(lD) : 0.f;
            den_part += wA + wB + wC + wD;
            v2f wA2 = {wA, wA}, wB2 = {wB, wB}, wC2 = {wC, wC}, wD2 = {wD, wD};
            accL += wA2 * fp8x2f<false>(hA);
            accH += wA2 * fp8x2f<true>(hA);
            accL += wB2 * fp8x2f<false>(hB);
            accH += wB2 * fp8x2f<true>(hB);
            accL += wC2 * fp8x2f<false>(hC);
            accH += wC2 * fp8x2f<true>(hC);
            accL += wD2 * fp8x2f<false>(hD);
            accH += wD2 * fp8x2f<true>(hD);
        }
        int rem = cntR - i;
        if (rem & 8) {  // 8 edges
            int eA = base + i + g, eB = eA + 4;
            int xB = eB < s1 ? eB : s1 - 1;
            int cA = col[eA], cB = col[xB];
            uint hA = *(const uint*)(h1f8 + ((((uint)cA) << 6) | co));
            uint hB = *(const uint*)(h1f8 + ((((uint)cB) << 6) | co));
            float lA = al1s[((((uint)cA) << 3) | (uint)hh)] + a_dh;
            float lB = al1s[((((uint)cB) << 3) | (uint)hh)] + a_dh;
            lA = lA > 0.f ? lA : 0.2f * lA;
            lB = lB > 0.f ? lB : 0.2f * lB;
            float wA = __expf(lA);
            float wB = (eB < s1) ? __expf(lB) : 0.f;
            den_part += wA + wB;
            v2f wA2 = {wA, wA}, wB2 = {wB, wB};
            accL += wA2 * fp8x2f<false>(hA);
            accH += wA2 * fp8x2f<true>(hA);
            accL += wB2 * fp8x2f<false>(hB);
            accH += wB2 * fp8x2f<true>(hB);
            i += 8;
        }
        if (rem & 4) {  // 4 edges
            int eA = base + i + g;
            int xA = eA < s1 ? eA : s1 - 1;
            int cA = col[xA];
            uint hA = *(const uint*)(h1f8 + ((((uint)cA) << 6) | co));
            float lA = al1s[((((uint)cA) << 3) | (uint)hh)] + a_dh;
            lA = lA > 0.f ? lA : 0.2f * lA;
            float wA = (eA < s1) ? __expf(lA) : 0.f;
            den_part += wA;
            v2f wA2 = {wA, wA};
            accL += wA2 * fp8x2f<false>(hA);
            accH += wA2 * fp8x2f<true>(hA);
        }
    }
    float a0 = accL.x, a1 = accL.y, a2 = accH.x, a3 = accH.y;
    a0 += __shfl_xor(a0, 16); a0 += __shfl_xor(a0, 32);
    a1 += __shfl_xor(a1, 16); a1 += __shfl_xor(a1, 32);
    a2 += __shfl_xor(a2, 16); a2 += __shfl_xor(a2, 32);
    a3 += __shfl_xor(a3, 16); a3 += __shfl_xor(a3, 32);
    den_part += __shfl_xor(den_part, 16);
    den_part += __shfl_xor(den_part, 32);   // per-lane den for head hh
    if (lane < 16) {
        float invd = 1.f / (den_part * S1);
        ((float4*)x1pre)[(size_t)node * 16 + k4] =
            make_float4(a0 * invd, a1 * invd, a2 * invd, a3 * invd);
    }
}

// ---- edge2p: 1024-thread blocks, 16 waves x 4 nodes; pooling fused via
// LDS accum per 64-node block (batch sorted -> <=2 graphs/block typical;
// 4 LDS slots + global-atomic fallback). ~215K global atomics total. ----
__global__ __launch_bounds__(1024) void k_edge2p(const uchar* __restrict__ h2f8,
                                                 const float* __restrict__ al2s,
                                                 const float* __restrict__ al2d,
                                                 const int* __restrict__ row_ptr,
                                                 const int* __restrict__ col,
                                                 const int* __restrict__ batchv,
                                                 float* __restrict__ pooled,
                                                 float* __restrict__ cntg, int N) {
    __shared__ float accum[4][128];
    __shared__ int scnt[4];
    __shared__ int sg0;
    const int tid = threadIdx.x;
    const int n0 = blockIdx.x * 64;
    if (tid < 512) accum[tid >> 7][tid & 127] = 0.f;
    if (tid < 4) scnt[tid] = 0;
    if (tid == 0) sg0 = batchv[n0];
    __syncthreads();
    const int g0 = sg0;
    const int w = tid >> 6;      // wave 0..15
    const int lane = tid & 63;
    const int g = lane >> 4;     // edge group 0..3
    const int k8 = lane & 15;    // channel oct
    const uint co = (uint)(k8 * 8);
    for (int j = 0; j < 4; ++j) {
        int node = n0 + w * 4 + j;
        if (node >= N) break;                 // uniform per wave
        const float a_d = al2d[node];
        const int s0 = row_ptr[node], s1 = row_ptr[node + 1];
        v2f acc0 = {0.f, 0.f}, acc1 = {0.f, 0.f}, acc2 = {0.f, 0.f}, acc3 = {0.f, 0.f};
        float den_part = 0.f;
        for (int base = s0; base < s1; base += 64) {
            int cnt = s1 - base; if (cnt > 64) cnt = 64;
            int cntR = (cnt + 3) & ~3;
            int i = 0;
            for (; i + 16 <= cntR; i += 16) {
                int eA = base + i + g, eB = eA + 4, eC = eA + 8, eD = eA + 12;
                int xD = eD < s1 ? eD : s1 - 1;
                int cA = col[eA], cB = col[eB], cC = col[eC], cD = col[xD];
                uint2 hA = *(const uint2*)(h2f8 + ((((uint)cA) << 7) | co));
                uint2 hB = *(const uint2*)(h2f8 + ((((uint)cB) << 7) | co));
                uint2 hC = *(const uint2*)(h2f8 + ((((uint)cC) << 7) | co));
                uint2 hD = *(const uint2*)(h2f8 + ((((uint)cD) << 7) | co));
                float lA = al2s[(uint)cA] + a_d;
                float lB = al2s[(uint)cB] + a_d;
                float lC = al2s[(uint)cC] + a_d;
                float lD = al2s[(uint)cD] + a_d;
                lA = lA > 0.f ? lA : 0.2f * lA;
                lB = lB > 0.f ? lB : 0.2f * lB;
                lC = lC > 0.f ? lC : 0.2f * lC;
                lD = lD > 0.f ? lD : 0.2f * lD;
                float wA = __expf(lA);
                float wB = __expf(lB);
                float wC = __expf(lC);
                float wD = (eD < s1) ? __expf(lD) : 0.f;
                den_part += wA + wB + wC + wD;
                v2f wA2 = {wA, wA}, wB2 = {wB, wB}, wC2 = {wC, wC}, wD2 = {wD, wD};
                acc0 += wA2 * fp8x2f<false>(hA.x);
                acc1 += wA2 * fp8x2f<true>(hA.x);
                acc2 += wA2 * fp8x2f<false>(hA.y);
                acc3 += wA2 * fp8x2f<true>(hA.y);
                acc0 += wB2 * fp8x2f<false>(hB.x);
                acc1 += wB2 * fp8x2f<true>(hB.x);
                acc2 += wB2 * fp8x2f<false>(hB.y);
                acc3 += wB2 * fp8x2f<true>(hB.y);
                acc0 += wC2 * fp8x2f<false>(hC.x);
                acc1 += wC2 * fp8x2f<true>(hC.x);
                acc2 += wC2 * fp8x2f<false>(hC.y);
                acc3 += wC2 * fp8x2f<true>(hC.y);
                acc0 += wD2 * fp8x2f<false>(hD.x);
                acc1 += wD2 * fp8x2f<true>(hD.x);
                acc2 += wD2 * fp8x2f<false>(hD.y);
                acc3 += wD2 * fp8x2f<true>(hD.y);
            }
            int rem = cntR - i;
            if (rem & 8) {
                int eA = base + i + g, eB = eA + 4;
                int xB = eB < s1 ? eB : s1 - 1;
                int cA = col[eA], cB = col[xB];
                uint2 hA = *(const uint2*)(h2f8 + ((((uint)cA) << 7) | co));
                uint2 hB = *(const uint2*)(h2f8 + ((((uint)cB) << 7) | co));
                float lA = al2s[(uint)cA] + a_d;
                float lB = al2s[(uint)cB] + a_d;
                lA = lA > 0.f ? lA : 0.2f * lA;
                lB = lB > 0.f ? lB : 0.2f * lB;
                float wA = __expf(lA);
                float wB = (eB < s1) ? __expf(lB) : 0.f;
                den_part += wA + wB;
                v2f wA2 = {wA, wA}, wB2 = {wB, wB};
                acc0 += wA2 * fp8x2f<false>(hA.x);
                acc1 += wA2 * fp8x2f<true>(hA.x);
                acc2 += wA2 * fp8x2f<false>(hA.y);
                acc3 += wA2 * fp8x2f<true>(hA.y);
                acc0 += wB2 * fp8x2f<false>(hB.x);
                acc1 += wB2 * fp8x2f<true>(hB.x);
                acc2 += wB2 * fp8x2f<false>(hB.y);
                acc3 += wB2 * fp8x2f<true>(hB.y);
                i += 8;
            }
            if (rem & 4) {
                int eA = base + i + g;
                int xA = eA < s1 ? eA : s1 - 1;
                int cA = col[xA];
                uint2 hA = *(const uint2*)(h2f8 + ((((uint)cA) << 7) | co));
                float lA = al2s[(uint)cA] + a_d;
                lA = lA > 0.f ? lA : 0.2f * lA;
                float wA = (eA < s1) ? __expf(lA) : 0.f;
                den_part += wA;
                v2f wA2 = {wA, wA};
                acc0 += wA2 * fp8x2f<false>(hA.x);
                acc1 += wA2 * fp8x2f<true>(hA.x);
                acc2 += wA2 * fp8x2f<false>(hA.y);
                acc3 += wA2 * fp8x2f<true>(hA.y);
            }
        }
        den_part += __shfl_xor(den_part, 16);
        den_part += __shfl_xor(den_part, 32);
        float r0 = acc0.x, r1 = acc0.y, r2 = acc1.x, r3 = acc1.y;
        float r4 = acc2.x, r5 = acc2.y, r6 = acc3.x, r7 = acc3.y;
        r0 += __shfl_xor(r0, 16); r0 += __shfl_xor(r0, 32);
        r1 += __shfl_xor(r1, 16); r1 += __shfl_xor(r1, 32);
        r2 += __shfl_xor(r2, 16); r2 += __shfl_xor(r2, 32);
        r3 += __shfl_xor(r3, 16); r3 += __shfl_xor(r3, 32);
        r4 += __shfl_xor(r4, 16); r4 += __shfl_xor(r4, 32);
        r5 += __shfl_xor(r5, 16); r5 += __shfl_xor(r5, 32);
        r6 += __shfl_xor(r6, 16); r6 += __shfl_xor(r6, 32);
        r7 += __shfl_xor(r7, 16); r7 += __shfl_xor(r7, 32);
        if (lane < 16) {
            float invd = 1.f / (den_part * S2);
            int slot = batchv[node] - g0;
            if (slot < 4) {
                float* pr = &accum[slot][co];
                atomicAdd(&pr[0], r0 * invd);
                atomicAdd(&pr[1], r1 * invd);
                atomicAdd(&pr[2], r2 * invd);
                atomicAdd(&pr[3], r3 * invd);
                atomicAdd(&pr[4], r4 * invd);
                atomicAdd(&pr[5], r5 * invd);
                atomicAdd(&pr[6], r6 * invd);
                atomicAdd(&pr[7], r7 * invd);
                if (k8 == 0) atomicAdd(&scnt[slot], 1);
            } else {  // rare fallback: graph spread > 4 within 64 nodes
                float* pr = pooled + (size_t)(g0 + slot) * 128 + co;
                atomicAdd(&pr[0], r0 * invd);
                atomicAdd(&pr[1], r1 * invd);
                atomicAdd(&pr[2], r2 * invd);
                atomicAdd(&pr[3], r3 * invd);
                atomicAdd(&pr[4], r4 * invd);
                atomicAdd(&pr[5], r5 * invd);
                atomicAdd(&pr[6], r6 * invd);
                atomicAdd(&pr[7], r7 * invd);
                if (k8 == 0) atomicAdd(&cntg[g0 + slot], 1.0f);
            }
        }
    }
    __syncthreads();
    if (tid < 512) {
        int slot = tid >> 7, ch = tid & 127;
        int c = scnt[slot];
        if (c > 0) {
            atomicAdd(&pooled[(size_t)(g0 + slot) * 128 + ch], accum[slot][ch]);
            if (ch == 0) atomicAdd(&cntg[g0 + slot], (float)c);
        }
    }
}

// ---- FC + log_softmax: one wave per graph (b2 folded in here: mean is linear) ----
__global__ __launch_bounds__(64) void k_fc(const float* __restrict__ pooled,
                                           const float* __restrict__ cnt,
                                           const float* __restrict__ b2,
                                           const float* __restrict__ fcw,
                                           const float* __restrict__ fcb,
                                           float* __restrict__ out, int G) {
    int g = blockIdx.x;
    int c = threadIdx.x;
    float2 p = ((const float2*)pooled)[(size_t)g * 64 + c];
    float2 bb = ((const float2*)b2)[c];
    float inv = 1.f / fmaxf(cnt[g], 1.f);
    p.x = p.x * inv + bb.x;
    p.y = p.y * inv + bb.y;
    float l[10];
#pragma unroll
    for (int j = 0; j < 10; ++j)
        l[j] = p.x * fcw[(2 * c) * 10 + j] + p.y * fcw[(2 * c + 1) * 10 + j];
#pragma unroll
    for (int j = 0; j < 10; ++j)
        for (int off = 1; off < 64; off <<= 1) l[j] += __shfl_xor(l[j], off);
    if (c == 0) {
        float lj[10];
        float m = -1e30f;
#pragma unroll
        for (int j = 0; j < 10; ++j) {
            lj[j] = l[j] + fcb[j];
            m = fmaxf(m, lj[j]);
        }
        float s = 0.f;
#pragma unroll
        for (int j = 0; j < 10; ++j) s += expf(lj[j] - m);
        float ls = logf(s);
#pragma unroll
        for (int j = 0; j < 10; ++j) out[(size_t)g * 10 + j] = lj[j] - m - ls;
    }
}

extern "C" void kernel_launch(void* const* d_in, const int* in_sizes, int n_in,
                              void* d_out, int out_size, void* d_ws, size_t ws_size,
                              hipStream_t stream) {
    const float* x     = (const float*)d_in[0];
    const int*   ei    = (const int*)d_in[1];
    const int*   batch = (const int*)d_in[2];
    const float* W1    = (const float*)d_in[3];
    const float* as1   = (const float*)d_in[4];
    const float* ad1   = (const float*)d_in[5];
    const float* b1    = (const float*)d_in[6];
    const float* W2    = (const float*)d_in[7];
    const float* as2   = (const float*)d_in[8];
    const float* ad2   = (const float*)d_in[9];
    const float* b2    = (const float*)d_in[10];
    const float* fcw   = (const float*)d_in[11];
    const float* fcb   = (const float*)d_in[12];
    float* out = (float*)d_out;

    const int N = in_sizes[0] / 128;
    const int E = in_sizes[1] / 2;
    const int G = out_size / 10;
    const int* srcp = ei;
    const int* dstp = ei + E;

    // workspace (float units):
    //   [0,16N)     h1f8 (N*64 fp8)   -- dead after k_edge1
    //   [16N,80N)   x1pre (f32 N*64)  -- dead after k_gemm2
    //   [128N,160N) h2f8 (N*128 fp8)
    //   [160N,168N) al1s  [168N,176N) al1d  [176N,177N) al2s  [177N,178N) al2d
    //   [178N,...)  pooled[G*128], cnt[G], then int region (ebuf, counts, btot, bbase, row_ptr, col)
    float* wf = (float*)d_ws;
    uchar* h1f8   = (uchar*)wf;
    float* x1pre  = wf + (size_t)N * 16;
    uchar* h2f8   = (uchar*)(wf + (size_t)N * 128);
    float* al1s_  = wf + (size_t)N * 160;
    float* al1d_  = wf + (size_t)N * 168;
    float* al2s_  = wf + (size_t)N * 176;
    float* al2d_  = wf + (size_t)N * 177;
    float* pooled = wf + (size_t)N * 178;
    float* cnt    = pooled + (size_t)G * 128;

    const int NB = (N + 127) >> 7;      // 782 buckets (requires NB <= 1024, LDS arrays 784)
    const int C  = 1024;                // histogram/scatter blocks
    const int CH = (E + C - 1) / C;     // edges per block

    int* ib = (int*)(((uintptr_t)(cnt + G) + 15) & ~(uintptr_t)15);
    int* ebuf    = ib;                              // [E] packed src|((dst&127)<<25)
    int* counts  = ib + (size_t)E;                  // [C*NB]
    int* btot    = counts + (size_t)C * NB;         // [NB]
    int* bbase   = btot + NB;                       // [NB+1]
    int* row_ptr = bbase + NB + 1;                  // [N+1]
    int* col     = row_ptr + N + 1;                 // [E+N]

    size_t zbytes = ((size_t)G * 128 + G) * sizeof(float);
    (void)hipMemsetAsync(pooled, 0, zbytes, stream);

    const int nb64 = (N + 63) / 64;
    const int nb4  = (N + 3) / 4;

    k_hist<<<C, 256, 0, stream>>>(dstp, counts, E, CH, NB);
    k_gemm1<<<nb64, 256, 0, stream>>>(x, W1, as1, ad1, h1f8, al1s_, al1d_, N);
    k_bscan<<<NB, 256, 0, stream>>>(counts, btot, C, NB);
    k_bucket<<<C, 256, 0, stream>>>(srcp, dstp, counts, btot, bbase, ebuf, E, CH, NB);
    k_csr<<<NB, 256, 0, stream>>>(bbase, ebuf, row_ptr, col, N, E);
    k_edge1<<<nb4, 256, 0, stream>>>(h1f8, al1s_, al1d_, row_ptr, col, x1pre, N);
    k_gemm2<<<nb64, 256, 0, stream>>>(x1pre, W2, b1, as2, ad2, h2f8, al2s_, al2d_, N);
    k_edge2p<<<nb64, 1024, 0, stream>>>(h2f8, al2s_, al2d_, row_ptr, col, batch, pooled, cnt, N);
    k_fc<<<G, 64, 0, stream>>>(pooled, cnt, b2, fcw, fcb, out, G);
}

// Round 5
// 340.904 us; speedup vs baseline: 1.1344x; 1.1344x over previous
//
#include <hip/hip_runtime.h>
#include <math.h>

typedef unsigned int uint;
typedef unsigned short ushort;
typedef unsigned char uchar;
typedef __attribute__((ext_vector_type(2))) float v2f;
typedef __attribute__((ext_vector_type(4))) _Float16 h4v;   // 8 B
typedef __attribute__((ext_vector_type(8))) _Float16 h8v;   // 16 B

#define S1 4.0f
#define S2 16.0f

template <bool HI>
__device__ inline v2f fp8x2f(uint u) {
    return __builtin_amdgcn_cvt_pk_f32_fp8((int)u, HI);
}

// ---- GEMM1: rec1[N] packed 128-B record {64B h1 fp8, 32B al1s f32, 32B al1d f32}
//      = x[N,128] @ W1[128,64]; one cache line per node for edge1 gathers ----
__global__ __launch_bounds__(256) void k_gemm1(const float* __restrict__ x,
                                               const float* __restrict__ W1,
                                               const float* __restrict__ as1,
                                               const float* __restrict__ ad1,
                                               uchar* __restrict__ rec1, int N) {
    __shared__ float sB[128 * 64];
    __shared__ float sA[64 * 68];
    const int t = threadIdx.x;
    const int n0 = blockIdx.x * 64;
    {
        const float4* w4 = (const float4*)W1;
        float4* s4 = (float4*)sB;
#pragma unroll
        for (int i = 0; i < 8; ++i) s4[t + i * 256] = w4[t + i * 256];
    }
    const int r0 = (t >> 3) * 2;
    const int c0 = (t & 7) * 8;   // head = t&7, channels c0..c0+7
    float acc0[8] = {0, 0, 0, 0, 0, 0, 0, 0};
    float acc1[8] = {0, 0, 0, 0, 0, 0, 0, 0};
    for (int kb = 0; kb < 2; ++kb) {
        __syncthreads();
#pragma unroll
        for (int i = 0; i < 4; ++i) {
            int idx = t + i * 256;
            int r = idx >> 4, kc = idx & 15;
            int n = n0 + r;
            float4 v = make_float4(0.f, 0.f, 0.f, 0.f);
            if (n < N) v = ((const float4*)x)[(size_t)n * 32 + kb * 16 + kc];
            *(float4*)&sA[r * 68 + kc * 4] = v;
        }
        __syncthreads();
        const float* bptr = &sB[kb * 64 * 64];
#pragma unroll 8
        for (int kk = 0; kk < 64; ++kk) {
            float a0 = sA[r0 * 68 + kk];
            float a1 = sA[(r0 + 1) * 68 + kk];
            const float* bp = &bptr[kk * 64 + c0];
            float4 b0 = *(const float4*)bp;
            float4 b1v = *(const float4*)(bp + 4);
            acc0[0] += a0 * b0.x; acc0[1] += a0 * b0.y; acc0[2] += a0 * b0.z; acc0[3] += a0 * b0.w;
            acc0[4] += a0 * b1v.x; acc0[5] += a0 * b1v.y; acc0[6] += a0 * b1v.z; acc0[7] += a0 * b1v.w;
            acc1[0] += a1 * b0.x; acc1[1] += a1 * b0.y; acc1[2] += a1 * b0.z; acc1[3] += a1 * b0.w;
            acc1[4] += a1 * b1v.x; acc1[5] += a1 * b1v.y; acc1[6] += a1 * b1v.z; acc1[7] += a1 * b1v.w;
        }
    }
    float ps0 = 0.f, pd0 = 0.f, ps1 = 0.f, pd1 = 0.f;
#pragma unroll
    for (int i = 0; i < 8; ++i) {
        float ws = as1[c0 + i], wd = ad1[c0 + i];
        ps0 += acc0[i] * ws; pd0 += acc0[i] * wd;
        ps1 += acc1[i] * ws; pd1 += acc1[i] * wd;
    }
    int n = n0 + r0;
    int head = t & 7;
    if (n < N) {
        int q0 = 0, q1 = 0;
        q0 = __builtin_amdgcn_cvt_pk_fp8_f32(acc0[0] * S1, acc0[1] * S1, q0, false);
        q0 = __builtin_amdgcn_cvt_pk_fp8_f32(acc0[2] * S1, acc0[3] * S1, q0, true);
        q1 = __builtin_amdgcn_cvt_pk_fp8_f32(acc0[4] * S1, acc0[5] * S1, q1, false);
        q1 = __builtin_amdgcn_cvt_pk_fp8_f32(acc0[6] * S1, acc0[7] * S1, q1, true);
        uint2 p; p.x = (uint)q0; p.y = (uint)q1;
        uchar* rp = rec1 + (size_t)n * 128;
        *(uint2*)(rp + c0) = p;
        *(float*)(rp + 64 + head * 4) = ps0;
        *(float*)(rp + 96 + head * 4) = pd0;
    }
    if (n + 1 < N) {
        int q0 = 0, q1 = 0;
        q0 = __builtin_amdgcn_cvt_pk_fp8_f32(acc1[0] * S1, acc1[1] * S1, q0, false);
        q0 = __builtin_amdgcn_cvt_pk_fp8_f32(acc1[2] * S1, acc1[3] * S1, q0, true);
        q1 = __builtin_amdgcn_cvt_pk_fp8_f32(acc1[4] * S1, acc1[5] * S1, q1, false);
        q1 = __builtin_amdgcn_cvt_pk_fp8_f32(acc1[6] * S1, acc1[7] * S1, q1, true);
        uint2 p; p.x = (uint)q0; p.y = (uint)q1;
        uchar* rp = rec1 + (size_t)(n + 1) * 128;
        *(uint2*)(rp + c0) = p;
        *(float*)(rp + 64 + head * 4) = ps1;
        *(float*)(rp + 96 + head * 4) = pd1;
    }
}

// ---- GEMM2: h2f8[N,128](fp8) = relu(x1pre(fp16)+b1) @ W2[64,128], fused al2 ----
__global__ __launch_bounds__(256) void k_gemm2(const _Float16* __restrict__ x1pre,
                                               const float* __restrict__ W2,
                                               const float* __restrict__ b1,
                                               const float* __restrict__ as2,
                                               const float* __restrict__ ad2,
                                               uchar* __restrict__ h2f8,
                                               float* __restrict__ al2s,
                                               float* __restrict__ al2d, int N) {
    __shared__ float sB[64 * 128];
    __shared__ float sA[64 * 68];
    const int t = threadIdx.x;
    const int n0 = blockIdx.x * 64;
    {
        const float4* w4 = (const float4*)W2;
        float4* s4 = (float4*)sB;
#pragma unroll
        for (int i = 0; i < 8; ++i) s4[t + i * 256] = w4[t + i * 256];
    }
#pragma unroll
    for (int i = 0; i < 4; ++i) {
        int idx = t + i * 256;
        int r = idx >> 4, kc = idx & 15;
        int n = n0 + r;
        float4 v = make_float4(0.f, 0.f, 0.f, 0.f);
        if (n < N) {
            h4v hv = *(const h4v*)(x1pre + (size_t)n * 64 + kc * 4);
            float4 bb = ((const float4*)b1)[kc];
            v.x = fmaxf((float)hv[0] + bb.x, 0.f);
            v.y = fmaxf((float)hv[1] + bb.y, 0.f);
            v.z = fmaxf((float)hv[2] + bb.z, 0.f);
            v.w = fmaxf((float)hv[3] + bb.w, 0.f);
        }
        *(float4*)&sA[r * 68 + kc * 4] = v;
    }
    __syncthreads();
    const int r0 = (t >> 3) * 2;
    const int cb = (t & 7) * 4;
    float acc0[16], acc1[16];
#pragma unroll
    for (int i = 0; i < 16; ++i) { acc0[i] = 0.f; acc1[i] = 0.f; }
#pragma unroll 4
    for (int k = 0; k < 64; ++k) {
        float a0 = sA[r0 * 68 + k];
        float a1 = sA[(r0 + 1) * 68 + k];
#pragma unroll
        for (int j = 0; j < 4; ++j) {
            float4 b = *(const float4*)&sB[k * 128 + cb + 32 * j];
            acc0[j * 4 + 0] += a0 * b.x; acc0[j * 4 + 1] += a0 * b.y;
            acc0[j * 4 + 2] += a0 * b.z; acc0[j * 4 + 3] += a0 * b.w;
            acc1[j * 4 + 0] += a1 * b.x; acc1[j * 4 + 1] += a1 * b.y;
            acc1[j * 4 + 2] += a1 * b.z; acc1[j * 4 + 3] += a1 * b.w;
        }
    }
    float ps0 = 0.f, pd0 = 0.f, ps1 = 0.f, pd1 = 0.f;
#pragma unroll
    for (int j = 0; j < 4; ++j)
#pragma unroll
        for (int i = 0; i < 4; ++i) {
            int cc = cb + 32 * j + i;
            float ws = as2[cc], wd = ad2[cc];
            ps0 += acc0[j * 4 + i] * ws; pd0 += acc0[j * 4 + i] * wd;
            ps1 += acc1[j * 4 + i] * ws; pd1 += acc1[j * 4 + i] * wd;
        }
#pragma unroll
    for (int off = 1; off < 8; off <<= 1) {
        ps0 += __shfl_xor(ps0, off); pd0 += __shfl_xor(pd0, off);
        ps1 += __shfl_xor(ps1, off); pd1 += __shfl_xor(pd1, off);
    }
    int n = n0 + r0;
    if (n < N) {
#pragma unroll
        for (int j = 0; j < 4; ++j) {
            int q = 0;
            q = __builtin_amdgcn_cvt_pk_fp8_f32(acc0[j * 4 + 0] * S2, acc0[j * 4 + 1] * S2, q, false);
            q = __builtin_amdgcn_cvt_pk_fp8_f32(acc0[j * 4 + 2] * S2, acc0[j * 4 + 3] * S2, q, true);
            *(uint*)&h2f8[(size_t)n * 128 + cb + 32 * j] = (uint)q;
        }
        if ((t & 7) == 0) { al2s[n] = ps0; al2d[n] = pd0; }
    }
    if (n + 1 < N) {
#pragma unroll
        for (int j = 0; j < 4; ++j) {
            int q = 0;
            q = __builtin_amdgcn_cvt_pk_fp8_f32(acc1[j * 4 + 0] * S2, acc1[j * 4 + 1] * S2, q, false);
            q = __builtin_amdgcn_cvt_pk_fp8_f32(acc1[j * 4 + 2] * S2, acc1[j * 4 + 3] * S2, q, true);
            *(uint*)&h2f8[(size_t)(n + 1) * 128 + cb + 32 * j] = (uint)q;
        }
        if ((t & 7) == 0) { al2s[n + 1] = ps1; al2d[n + 1] = pd1; }
    }
}

// ========== atomic-free CSR build: two-level counting sort ==========

// pass A: per-block LDS histogram over buckets
__global__ __launch_bounds__(256) void k_hist(const int* __restrict__ dst,
                                              int* __restrict__ counts,
                                              int E, int CH, int NB) {
    __shared__ int hist[784];
    int t = threadIdx.x, b = blockIdx.x;
    for (int k = t; k < NB; k += 256) hist[k] = 0;
    __syncthreads();
    int e0 = b * CH;
    int e1 = e0 + CH; if (e1 > E) e1 = E;
    for (int e = e0 + t; e < e1; e += 256)
        atomicAdd(&hist[dst[e] >> 7], 1);
    __syncthreads();
    for (int k = t; k < NB; k += 256) counts[(size_t)b * NB + k] = hist[k];
}

// pass B: per-bucket exclusive scan over blocks (one block per bucket)
__global__ __launch_bounds__(256) void k_bscan(int* __restrict__ counts,
                                               int* __restrict__ btot,
                                               int C, int NB) {
    __shared__ int sh[256];
    int t = threadIdx.x, k = blockIdx.x;
    int v[4];
#pragma unroll
    for (int i = 0; i < 4; ++i) {
        int b = t * 4 + i;
        v[i] = (b < C) ? counts[(size_t)b * NB + k] : 0;
    }
    int s = v[0] + v[1] + v[2] + v[3];
    sh[t] = s;
    __syncthreads();
    int accv = s;
    for (int off = 1; off < 256; off <<= 1) {
        int u = (t >= off) ? sh[t - off] : 0;
        __syncthreads();
        accv += u;
        sh[t] = accv;
        __syncthreads();
    }
    int excl = accv - s;
#pragma unroll
    for (int i = 0; i < 4; ++i) {
        int b = t * 4 + i;
        if (b < C) counts[(size_t)b * NB + k] = excl;
        excl += v[i];
    }
    if (t == 255) btot[k] = accv;
}

// pass D: scatter edges into bucket-sorted ebuf; bbase scan folded in
__global__ __launch_bounds__(256) void k_bucket(const int* __restrict__ src,
                                                const int* __restrict__ dst,
                                                const int* __restrict__ counts,
                                                const int* __restrict__ btot,
                                                int* __restrict__ bbase,
                                                int* __restrict__ ebuf,
                                                int E, int CH, int NB) {
    __shared__ int pos[784];
    __shared__ int sh[256];
    __shared__ int bb[784];
    int t = threadIdx.x, b = blockIdx.x;
    int v[4];
#pragma unroll
    for (int i = 0; i < 4; ++i) {
        int k = t * 4 + i;
        v[i] = (k < NB) ? btot[k] : 0;
    }
    int s = v[0] + v[1] + v[2] + v[3];
    sh[t] = s;
    __syncthreads();
    int accv = s;
    for (int off = 1; off < 256; off <<= 1) {
        int u = (t >= off) ? sh[t - off] : 0;
        __syncthreads();
        accv += u;
        sh[t] = accv;
        __syncthreads();
    }
    int excl = accv - s;
#pragma unroll
    for (int i = 0; i < 4; ++i) {
        int k = t * 4 + i;
        if (k < NB) bb[k] = excl;
        excl += v[i];
    }
    __syncthreads();
    for (int k = t; k < NB; k += 256)
        pos[k] = bb[k] + counts[(size_t)b * NB + k];
    if (b == 0) {
        for (int k = t; k < NB; k += 256) bbase[k] = bb[k];
        if (t == 0) bbase[NB] = E;
    }
    __syncthreads();
    int e0 = b * CH;
    int e1 = e0 + CH; if (e1 > E) e1 = E;
    for (int e = e0 + t; e < e1; e += 256) {
        int d = dst[e], s2 = src[e];
        int p = atomicAdd(&pos[d >> 7], 1);
        ebuf[p] = (int)((uint)s2 | ((uint)(d & 127) << 25));
    }
}

// pass E: per-bucket fine CSR
__global__ __launch_bounds__(256) void k_csr(const int* __restrict__ bbase,
                                             const int* __restrict__ ebuf,
                                             int* __restrict__ row_ptr,
                                             int* __restrict__ col,
                                             int N, int E) {
    __shared__ int cnt[128];
    __shared__ int fill[128];
    __shared__ int rowb[128];
    __shared__ int sh[256];
    int t = threadIdx.x, k = blockIdx.x;
    int lo = bbase[k], hi = bbase[k + 1];
    int nlo = k << 7;
    int nn = N - nlo; if (nn > 128) nn = 128;
    if (t < 128) { cnt[t] = 0; fill[t] = 0; }
    __syncthreads();
    for (int i = lo + t; i < hi; i += 256)
        atomicAdd(&cnt[((uint)ebuf[i]) >> 25], 1);
    __syncthreads();
    int v = (t < nn) ? (cnt[t] + 1) : 0;  // +1 self-loop slot
    sh[t] = v;
    __syncthreads();
    int accv = v;
    for (int off = 1; off < 256; off <<= 1) {
        int u = (t >= off) ? sh[t - off] : 0;
        __syncthreads();
        accv += u;
        sh[t] = accv;
        __syncthreads();
    }
    int fbase = lo + nlo;
    if (t < nn) {
        int rb = fbase + accv - v;
        rowb[t] = rb;
        row_ptr[nlo + t] = rb;
        col[rb + cnt[t]] = nlo + t;  // self-loop at end of row
    }
    if (k == 0 && t == 0) row_ptr[N] = E + N;
    __syncthreads();
    for (int i = lo + t; i < hi; i += 256) {
        uint e = (uint)ebuf[i];
        int j = (int)(e >> 25);
        int r = atomicAdd(&fill[j], 1);
        col[rowb[j] + r] = (int)(e & 0x1FFFFFFu);
    }
}

// ---- edge1: wave/node, shfl-free; ONE 128-B line per edge (packed rec1) ----
__global__ __launch_bounds__(256) void k_edge1(const uchar* __restrict__ rec1,
                                               const int* __restrict__ row_ptr,
                                               const int* __restrict__ col,
                                               _Float16* __restrict__ x1pre, int N) {
    int node = blockIdx.x * 4 + (threadIdx.x >> 6);
    if (node >= N) return;
    const int lane = threadIdx.x & 63;
    const int g = lane >> 4;       // edge subgroup 0..3
    const int k4 = lane & 15;      // channel quad (ch 4k4..4k4+3)
    const int hh = k4 >> 1;        // head of those channels
    const uint co = (uint)(k4 * 4);
    const uint ao = 64u + (uint)(hh * 4);
    const float a_dh = *(const float*)(rec1 + (((size_t)node) << 7) + 96 + hh * 4);
    const int s0 = row_ptr[node], s1 = row_ptr[node + 1];
    float den_part = 0.f;
    v2f accL = {0.f, 0.f};
    v2f accH = {0.f, 0.f};
    for (int base = s0; base < s1; base += 64) {
        int cnt = s1 - base; if (cnt > 64) cnt = 64;
        int cntR = (cnt + 3) & ~3;
        int i = 0;
        for (; i + 16 <= cntR; i += 16) {
            int eA = base + i + g, eB = eA + 4, eC = eA + 8, eD = eA + 12;
            int xD = eD < s1 ? eD : s1 - 1;       // only D can run past
            int cA = col[eA], cB = col[eB], cC = col[eC], cD = col[xD];
            const uchar* rA = rec1 + (((uint)cA) << 7);
            const uchar* rB = rec1 + (((uint)cB) << 7);
            const uchar* rC = rec1 + (((uint)cC) << 7);
            const uchar* rD = rec1 + (((uint)cD) << 7);
            uint hA = *(const uint*)(rA + co);
            uint hB = *(const uint*)(rB + co);
            uint hC = *(const uint*)(rC + co);
            uint hD = *(const uint*)(rD + co);
            float lA = *(const float*)(rA + ao) + a_dh;
            float lB = *(const float*)(rB + ao) + a_dh;
            float lC = *(const float*)(rC + ao) + a_dh;
            float lD = *(const float*)(rD + ao) + a_dh;
            lA = lA > 0.f ? lA : 0.2f * lA;
            lB = lB > 0.f ? lB : 0.2f * lB;
            lC = lC > 0.f ? lC : 0.2f * lC;
            lD = lD > 0.f ? lD : 0.2f * lD;
            float wA = __expf(lA);
            float wB = __expf(lB);
            float wC = __expf(lC);
            float wD = (eD < s1) ? __expf(lD) : 0.f;
            den_part += wA + wB + wC + wD;
            v2f wA2 = {wA, wA}, wB2 = {wB, wB}, wC2 = {wC, wC}, wD2 = {wD, wD};
            accL += wA2 * fp8x2f<false>(hA);
            accH += wA2 * fp8x2f<true>(hA);
            accL += wB2 * fp8x2f<false>(hB);
            accH += wB2 * fp8x2f<true>(hB);
            accL += wC2 * fp8x2f<false>(hC);
            accH += wC2 * fp8x2f<true>(hC);
            accL += wD2 * fp8x2f<false>(hD);
            accH += wD2 * fp8x2f<true>(hD);
        }
        int rem = cntR - i;
        if (rem & 8) {  // 8 edges
            int eA = base + i + g, eB = eA + 4;
            int xB = eB < s1 ? eB : s1 - 1;
            int cA = col[eA], cB = col[xB];
            const uchar* rA = rec1 + (((uint)cA) << 7);
            const uchar* rB = rec1 + (((uint)cB) << 7);
            uint hA = *(const uint*)(rA + co);
            uint hB = *(const uint*)(rB + co);
            float lA = *(const float*)(rA + ao) + a_dh;
            float lB = *(const float*)(rB + ao) + a_dh;
            lA = lA > 0.f ? lA : 0.2f * lA;
            lB = lB > 0.f ? lB : 0.2f * lB;
            float wA = __expf(lA);
            float wB = (eB < s1) ? __expf(lB) : 0.f;
            den_part += wA + wB;
            v2f wA2 = {wA, wA}, wB2 = {wB, wB};
            accL += wA2 * fp8x2f<false>(hA);
            accH += wA2 * fp8x2f<true>(hA);
            accL += wB2 * fp8x2f<false>(hB);
            accH += wB2 * fp8x2f<true>(hB);
            i += 8;
        }
        if (rem & 4) {  // 4 edges
            int eA = base + i + g;
            int xA = eA < s1 ? eA : s1 - 1;
            int cA = col[xA];
            const uchar* rA = rec1 + (((uint)cA) << 7);
            uint hA = *(const uint*)(rA + co);
            float lA = *(const float*)(rA + ao) + a_dh;
            lA = lA > 0.f ? lA : 0.2f * lA;
            float wA = (eA < s1) ? __expf(lA) : 0.f;
            den_part += wA;
            v2f wA2 = {wA, wA};
            accL += wA2 * fp8x2f<false>(hA);
            accH += wA2 * fp8x2f<true>(hA);
        }
    }
    float a0 = accL.x, a1 = accL.y, a2 = accH.x, a3 = accH.y;
    a0 += __shfl_xor(a0, 16); a0 += __shfl_xor(a0, 32);
    a1 += __shfl_xor(a1, 16); a1 += __shfl_xor(a1, 32);
    a2 += __shfl_xor(a2, 16); a2 += __shfl_xor(a2, 32);
    a3 += __shfl_xor(a3, 16); a3 += __shfl_xor(a3, 32);
    den_part += __shfl_xor(den_part, 16);
    den_part += __shfl_xor(den_part, 32);   // per-lane den for head hh
    if (lane < 16) {
        float invd = 1.f / (den_part * S1);
        h4v o;
        o[0] = (_Float16)(a0 * invd);
        o[1] = (_Float16)(a1 * invd);
        o[2] = (_Float16)(a2 * invd);
        o[3] = (_Float16)(a3 * invd);
        *(h4v*)(x1pre + (size_t)node * 64 + co) = o;
    }
}

// ---- edge2: wave/node, shfl-free; writes x2 as fp16 (b2 deferred to k_fc) ----
__global__ __launch_bounds__(256) void k_edge2(const uchar* __restrict__ h2f8,
                                               const float* __restrict__ al2s,
                                               const float* __restrict__ al2d,
                                               const int* __restrict__ row_ptr,
                                               const int* __restrict__ col,
                                               _Float16* __restrict__ x2, int N) {
    int node = blockIdx.x * 4 + (threadIdx.x >> 6);
    if (node >= N) return;
    const int lane = threadIdx.x & 63;
    const int g = lane >> 4;    // edge group 0..3
    const int k8 = lane & 15;   // channel oct (ch 8k8..8k8+7 of 128)
    const uint co = (uint)(k8 * 8);
    const float a_d = al2d[node];
    const int s0 = row_ptr[node], s1 = row_ptr[node + 1];
    v2f acc0 = {0.f, 0.f}, acc1 = {0.f, 0.f}, acc2 = {0.f, 0.f}, acc3 = {0.f, 0.f};
    float den_part = 0.f;
    for (int base = s0; base < s1; base += 64) {
        int cnt = s1 - base; if (cnt > 64) cnt = 64;
        int cntR = (cnt + 3) & ~3;
        int i = 0;
        for (; i + 16 <= cntR; i += 16) {
            int eA = base + i + g, eB = eA + 4, eC = eA + 8, eD = eA + 12;
            int xD = eD < s1 ? eD : s1 - 1;
            int cA = col[eA], cB = col[eB], cC = col[eC], cD = col[xD];
            uint2 hA = *(const uint2*)(h2f8 + ((((uint)cA) << 7) | co));
            uint2 hB = *(const uint2*)(h2f8 + ((((uint)cB) << 7) | co));
            uint2 hC = *(const uint2*)(h2f8 + ((((uint)cC) << 7) | co));
            uint2 hD = *(const uint2*)(h2f8 + ((((uint)cD) << 7) | co));
            float lA = al2s[(uint)cA] + a_d;
            float lB = al2s[(uint)cB] + a_d;
            float lC = al2s[(uint)cC] + a_d;
            float lD = al2s[(uint)cD] + a_d;
            lA = lA > 0.f ? lA : 0.2f * lA;
            lB = lB > 0.f ? lB : 0.2f * lB;
            lC = lC > 0.f ? lC : 0.2f * lC;
            lD = lD > 0.f ? lD : 0.2f * lD;
            float wA = __expf(lA);
            float wB = __expf(lB);
            float wC = __expf(lC);
            float wD = (eD < s1) ? __expf(lD) : 0.f;
            den_part += wA + wB + wC + wD;
            v2f wA2 = {wA, wA}, wB2 = {wB, wB}, wC2 = {wC, wC}, wD2 = {wD, wD};
            acc0 += wA2 * fp8x2f<false>(hA.x);
            acc1 += wA2 * fp8x2f<true>(hA.x);
            acc2 += wA2 * fp8x2f<false>(hA.y);
            acc3 += wA2 * fp8x2f<true>(hA.y);
            acc0 += wB2 * fp8x2f<false>(hB.x);
            acc1 += wB2 * fp8x2f<true>(hB.x);
            acc2 += wB2 * fp8x2f<false>(hB.y);
            acc3 += wB2 * fp8x2f<true>(hB.y);
            acc0 += wC2 * fp8x2f<false>(hC.x);
            acc1 += wC2 * fp8x2f<true>(hC.x);
            acc2 += wC2 * fp8x2f<false>(hC.y);
            acc3 += wC2 * fp8x2f<true>(hC.y);
            acc0 += wD2 * fp8x2f<false>(hD.x);
            acc1 += wD2 * fp8x2f<true>(hD.x);
            acc2 += wD2 * fp8x2f<false>(hD.y);
            acc3 += wD2 * fp8x2f<true>(hD.y);
        }
        int rem = cntR - i;
        if (rem & 8) {
            int eA = base + i + g, eB = eA + 4;
            int xB = eB < s1 ? eB : s1 - 1;
            int cA = col[eA], cB = col[xB];
            uint2 hA = *(const uint2*)(h2f8 + ((((uint)cA) << 7) | co));
            uint2 hB = *(const uint2*)(h2f8 + ((((uint)cB) << 7) | co));
            float lA = al2s[(uint)cA] + a_d;
            float lB = al2s[(uint)cB] + a_d;
            lA = lA > 0.f ? lA : 0.2f * lA;
            lB = lB > 0.f ? lB : 0.2f * lB;
            float wA = __expf(lA);
            float wB = (eB < s1) ? __expf(lB) : 0.f;
            den_part += wA + wB;
            v2f wA2 = {wA, wA}, wB2 = {wB, wB};
            acc0 += wA2 * fp8x2f<false>(hA.x);
            acc1 += wA2 * fp8x2f<true>(hA.x);
            acc2 += wA2 * fp8x2f<false>(hA.y);
            acc3 += wA2 * fp8x2f<true>(hA.y);
            acc0 += wB2 * fp8x2f<false>(hB.x);
            acc1 += wB2 * fp8x2f<true>(hB.x);
            acc2 += wB2 * fp8x2f<false>(hB.y);
            acc3 += wB2 * fp8x2f<true>(hB.y);
            i += 8;
        }
        if (rem & 4) {
            int eA = base + i + g;
            int xA = eA < s1 ? eA : s1 - 1;
            int cA = col[xA];
            uint2 hA = *(const uint2*)(h2f8 + ((((uint)cA) << 7) | co));
            float lA = al2s[(uint)cA] + a_d;
            lA = lA > 0.f ? lA : 0.2f * lA;
            float wA = (eA < s1) ? __expf(lA) : 0.f;
            den_part += wA;
            v2f wA2 = {wA, wA};
            acc0 += wA2 * fp8x2f<false>(hA.x);
            acc1 += wA2 * fp8x2f<true>(hA.x);
            acc2 += wA2 * fp8x2f<false>(hA.y);
            acc3 += wA2 * fp8x2f<true>(hA.y);
        }
    }
    den_part += __shfl_xor(den_part, 16);
    den_part += __shfl_xor(den_part, 32);
    float r0 = acc0.x, r1 = acc0.y, r2 = acc1.x, r3 = acc1.y;
    float r4 = acc2.x, r5 = acc2.y, r6 = acc3.x, r7 = acc3.y;
    r0 += __shfl_xor(r0, 16); r0 += __shfl_xor(r0, 32);
    r1 += __shfl_xor(r1, 16); r1 += __shfl_xor(r1, 32);
    r2 += __shfl_xor(r2, 16); r2 += __shfl_xor(r2, 32);
    r3 += __shfl_xor(r3, 16); r3 += __shfl_xor(r3, 32);
    r4 += __shfl_xor(r4, 16); r4 += __shfl_xor(r4, 32);
    r5 += __shfl_xor(r5, 16); r5 += __shfl_xor(r5, 32);
    r6 += __shfl_xor(r6, 16); r6 += __shfl_xor(r6, 32);
    r7 += __shfl_xor(r7, 16); r7 += __shfl_xor(r7, 32);
    if (lane < 16) {
        float invd = 1.f / (den_part * S2);
        h8v o;
        o[0] = (_Float16)(r0 * invd);
        o[1] = (_Float16)(r1 * invd);
        o[2] = (_Float16)(r2 * invd);
        o[3] = (_Float16)(r3 * invd);
        o[4] = (_Float16)(r4 * invd);
        o[5] = (_Float16)(r5 * invd);
        o[6] = (_Float16)(r6 * invd);
        o[7] = (_Float16)(r7 * invd);
        *(h8v*)(x2 + (size_t)node * 128 + co) = o;
    }
}

// ---- mean pool over sorted batch (fp16 input, run-length chunked atomics) ----
__global__ __launch_bounds__(128) void k_pool(const _Float16* __restrict__ x2,
                                              const int* __restrict__ batch,
                                              float* __restrict__ pooled,
                                              float* __restrict__ cnt, int N) {
    int t = threadIdx.x;
    int nstart = blockIdx.x * 128;
    if (nstart >= N) return;
    int nend = nstart + 128;
    if (nend > N) nend = N;
    float acc = 0.f;
    int cur = batch[nstart];
    int count = 0;
    for (int n = nstart; n < nend; ++n) {
        int g = batch[n];
        if (g != cur) {
            atomicAdd(&pooled[(size_t)cur * 128 + t], acc);
            if (t == 0) atomicAdd(&cnt[cur], (float)count);
            acc = 0.f;
            count = 0;
            cur = g;
        }
        acc += (float)x2[(size_t)n * 128 + t];
        ++count;
    }
    atomicAdd(&pooled[(size_t)cur * 128 + t], acc);
    if (t == 0) atomicAdd(&cnt[cur], (float)count);
}

// ---- FC + log_softmax: one wave per graph (b2 folded in: mean is linear) ----
__global__ __launch_bounds__(64) void k_fc(const float* __restrict__ pooled,
                                           const float* __restrict__ cnt,
                                           const float* __restrict__ b2,
                                           const float* __restrict__ fcw,
                                           const float* __restrict__ fcb,
                                           float* __restrict__ out, int G) {
    int g = blockIdx.x;
    int c = threadIdx.x;
    float2 p = ((const float2*)pooled)[(size_t)g * 64 + c];
    float2 bb = ((const float2*)b2)[c];
    float inv = 1.f / fmaxf(cnt[g], 1.f);
    p.x = p.x * inv + bb.x;
    p.y = p.y * inv + bb.y;
    float l[10];
#pragma unroll
    for (int j = 0; j < 10; ++j)
        l[j] = p.x * fcw[(2 * c) * 10 + j] + p.y * fcw[(2 * c + 1) * 10 + j];
#pragma unroll
    for (int j = 0; j < 10; ++j)
        for (int off = 1; off < 64; off <<= 1) l[j] += __shfl_xor(l[j], off);
    if (c == 0) {
        float lj[10];
        float m = -1e30f;
#pragma unroll
        for (int j = 0; j < 10; ++j) {
            lj[j] = l[j] + fcb[j];
            m = fmaxf(m, lj[j]);
        }
        float s = 0.f;
#pragma unroll
        for (int j = 0; j < 10; ++j) s += expf(lj[j] - m);
        float ls = logf(s);
#pragma unroll
        for (int j = 0; j < 10; ++j) out[(size_t)g * 10 + j] = lj[j] - m - ls;
    }
}

extern "C" void kernel_launch(void* const* d_in, const int* in_sizes, int n_in,
                              void* d_out, int out_size, void* d_ws, size_t ws_size,
                              hipStream_t stream) {
    const float* x     = (const float*)d_in[0];
    const int*   ei    = (const int*)d_in[1];
    const int*   batch = (const int*)d_in[2];
    const float* W1    = (const float*)d_in[3];
    const float* as1   = (const float*)d_in[4];
    const float* ad1   = (const float*)d_in[5];
    const float* b1    = (const float*)d_in[6];
    const float* W2    = (const float*)d_in[7];
    const float* as2   = (const float*)d_in[8];
    const float* ad2   = (const float*)d_in[9];
    const float* b2    = (const float*)d_in[10];
    const float* fcw   = (const float*)d_in[11];
    const float* fcb   = (const float*)d_in[12];
    float* out = (float*)d_out;

    const int N = in_sizes[0] / 128;
    const int E = in_sizes[1] / 2;
    const int G = out_size / 10;
    const int* srcp = ei;
    const int* dstp = ei + E;

    // workspace (float units):
    //   [0,32N)     rec1 (N x 128B packed: h1 fp8 + al1s + al1d) -- dead after k_edge1
    //   [32N,64N)   x1pre (fp16 N*64)                            -- dead after k_gemm2
    //   [0,64N)     x2 (fp16 N*128) -- aliases dead rec1/x1pre
    //   [128N,160N) h2f8 (N*128 fp8)
    //   [176N,177N) al2s  [177N,178N) al2d
    //   [178N,...)  pooled[G*128], cnt[G], then int region
    float* wf = (float*)d_ws;
    uchar*    rec1  = (uchar*)wf;
    _Float16* x1pre = (_Float16*)(wf + (size_t)N * 32);
    _Float16* x2    = (_Float16*)wf;
    uchar*    h2f8  = (uchar*)(wf + (size_t)N * 128);
    float* al2s_  = wf + (size_t)N * 176;
    float* al2d_  = wf + (size_t)N * 177;
    float* pooled = wf + (size_t)N * 178;
    float* cnt    = pooled + (size_t)G * 128;

    const int NB = (N + 127) >> 7;      // 782 buckets (requires NB <= 1024)
    const int C  = 1024;                // histogram/scatter blocks
    const int CH = (E + C - 1) / C;     // edges per block

    int* ib = (int*)(((uintptr_t)(cnt + G) + 15) & ~(uintptr_t)15);
    int* ebuf    = ib;                              // [E] packed src|((dst&127)<<25)
    int* counts  = ib + (size_t)E;                  // [C*NB]
    int* btot    = counts + (size_t)C * NB;         // [NB]
    int* bbase   = btot + NB;                       // [NB+1]
    int* row_ptr = bbase + NB + 1;                  // [N+1]
    int* col     = row_ptr + N + 1;                 // [E+N]

    size_t zbytes = ((size_t)G * 128 + G) * sizeof(float);
    (void)hipMemsetAsync(pooled, 0, zbytes, stream);

    const int nb64 = (N + 63) / 64;
    const int nb4  = (N + 3) / 4;
    const int nbP  = (N + 127) / 128;

    k_hist<<<C, 256, 0, stream>>>(dstp, counts, E, CH, NB);
    k_gemm1<<<nb64, 256, 0, stream>>>(x, W1, as1, ad1, rec1, N);
    k_bscan<<<NB, 256, 0, stream>>>(counts, btot, C, NB);
    k_bucket<<<C, 256, 0, stream>>>(srcp, dstp, counts, btot, bbase, ebuf, E, CH, NB);
    k_csr<<<NB, 256, 0, stream>>>(bbase, ebuf, row_ptr, col, N, E);
    k_edge1<<<nb4, 256, 0, stream>>>(rec1, row_ptr, col, x1pre, N);
    k_gemm2<<<nb64, 256, 0, stream>>>(x1pre, W2, b1, as2, ad2, h2f8, al2s_, al2d_, N);
    k_edge2<<<nb4, 256, 0, stream>>>(h2f8, al2s_, al2d_, row_ptr, col, x2, N);
    k_pool<<<nbP, 128, 0, stream>>>(x2, batch, pooled, cnt, N);
    k_fc<<<G, 64, 0, stream>>>(pooled, cnt, b2, fcw, fcb, out, G);
}